// Round 15
// baseline (163.912 us; speedup 1.0000x reference)
//
#include <hip/hip_runtime.h>
#include <stdint.h>

typedef _Float16 f16;
typedef _Float16 f16x8 __attribute__((ext_vector_type(8)));
typedef _Float16 f16x4 __attribute__((ext_vector_type(4)));
typedef float f32x4 __attribute__((ext_vector_type(4)));

constexpr int EMB = 512;
constexpr int SEQ = 1024;
constexpr int NH = 8;
constexpr int DHEAD = 64;
constexpr int NTOK = 8192;  // B*S

#define GAS __attribute__((address_space(1)))
#define LAS __attribute__((address_space(3)))

#if __has_builtin(__builtin_amdgcn_exp2f)
#define EXP2F(x) __builtin_amdgcn_exp2f(x)
#else
#define EXP2F(x) exp2f(x)
#endif

static __device__ __forceinline__ void gload_lds16(const void* g, void* l) {
  __builtin_amdgcn_global_load_lds((const GAS void*)g, (LAS void*)l, 16, 0, 0);
}

// ---------------- weight / input packing ----------------

__global__ void k_pack_w(const float* __restrict__ Wq, const float* __restrict__ Wk,
                         const float* __restrict__ Wv, const float* __restrict__ Wo,
                         f16* __restrict__ wqkv, f16* __restrict__ wo) {
  int tid = blockIdx.x * 256 + threadIdx.x;
  if (tid < 2 * 1536 * 128) {  // qkv: [L][1536][512], 4 elems/thread
    int e4 = tid & 127;
    int f = (tid >> 7) % 1536;
    int l = tid / (128 * 1536);
    int part = f >> 9, fr = f & 511;
    const float* src = (part == 0 ? Wq : part == 1 ? Wk : Wv) + (size_t)l * EMB * EMB + (size_t)fr * EMB + e4 * 4;
    float4 v = *(const float4*)src;
    f16x4 hv = {(f16)v.x, (f16)v.y, (f16)v.z, (f16)v.w};
    *(f16x4*)(wqkv + ((size_t)l * 1536 + f) * EMB + e4 * 4) = hv;
  }
  if (tid < 2 * 512 * 128) {  // wo: [L][512][512]
    int e4 = tid & 127;
    int f = (tid >> 7) % 512;
    int l = tid / (128 * 512);
    float4 v = *(const float4*)(Wo + (size_t)l * EMB * EMB + (size_t)f * EMB + e4 * 4);
    f16x4 hv = {(f16)v.x, (f16)v.y, (f16)v.z, (f16)v.w};
    *(f16x4*)(wo + ((size_t)l * 512 + f) * EMB + e4 * 4) = hv;
  }
}

__global__ void k_pack_b(const float* __restrict__ bq, const float* __restrict__ bk,
                         const float* __restrict__ bv, float* __restrict__ bqkv) {
  int tid = blockIdx.x * 256 + threadIdx.x;
  if (tid < 2 * 1536) {
    int f = tid % 1536, l = tid / 1536;
    int part = f >> 9, fr = f & 511;
    bqkv[tid] = (part == 0 ? bq : part == 1 ? bk : bv)[l * EMB + fr];
  }
}

__global__ void k_cvt(const float* __restrict__ x, f16* __restrict__ out) {
  int i = (blockIdx.x * 256 + threadIdx.x) * 8;
  float4 a = *(const float4*)(x + i);
  float4 b = *(const float4*)(x + i + 4);
  f16x8 h = {(f16)a.x, (f16)a.y, (f16)a.z, (f16)a.w, (f16)b.x, (f16)b.y, (f16)b.z, (f16)b.w};
  *(f16x8*)(out + i) = h;
}

// adj -> f16 pre-scaled by 0.125*log2(e), packed in MFMA C-fragment order:
// adjP[((qrow*16 + tile)*16 + lanelow)*4 + n] = adj[qrow][tile*64 + n*16 + lanelow] * c
__global__ void k_pack_adjP(const float* __restrict__ adj, f16* __restrict__ adjP) {
  int tid = blockIdx.x * 256 + threadIdx.x;  // 262144 total
  int lo = tid & 15, t = (tid >> 4) & 15, qrow = tid >> 8;
  const float c = 0.125f * 1.44269504088896f;
  const float* row = adj + (size_t)qrow * SEQ + t * 64 + lo;
  f16x4 v = {(f16)(row[0] * c), (f16)(row[16] * c), (f16)(row[32] * c), (f16)(row[48] * c)};
  *(f16x4*)(adjP + (size_t)tid * 4) = v;
}

// ---------------- GEMM: C[M,N] = A[M,512] * Bw[N,512]^T + bias ----------------
// R14: 8-wave blocks (the R12/R13 attn-verified structure ported to GEMM).
// 512 threads, waves 4x2, each wave owns 32x64 (acc 2x4). BK=64 -> 8 K-steps
// (half the barriers of R13's BK=32/16-step shape). 2-buffer LDS (64KB ->
// 2 blocks/CU = 16 waves/CU, up from 12): STAGE(t+1) at top, one __syncthreads
// at end -- byte-identical sync skeleton to the 35us attn.
// MODE 0: write f16 U (grid 256). MODE 1: scatter Q,K,V^T (grid 768).

template <int MODE>
__global__ __launch_bounds__(512) void k_gemm(const f16* __restrict__ A, const f16* __restrict__ Bw,
                                              const float* __restrict__ bias, f16* __restrict__ Uout,
                                              f16* __restrict__ Qo, f16* __restrict__ Ko,
                                              f16* __restrict__ Vt) {
  __shared__ f16x8 sA[2][1024];  // [buf][128 rows x 8 chunks] = 16KB each
  __shared__ f16x8 sB[2][1024];
  const int tid = threadIdx.x;
  const int lane = tid & 63;
  const int lanelow = lane & 15, lanehi = lane >> 4;
  const int wave = tid >> 6;          // [0,8)
  const int wm = wave >> 1;           // [0,4) -> 32-row slab
  const int wn = wave & 1;            // [0,2) -> 64-col slab
  const int flat = blockIdx.x;
  const int mt = (flat & 7) * 8 + ((flat >> 3) & 7);
  const int nt = flat >> 6;
  const int m0 = mt * 128, n0 = nt * 128;

  f32x4 acc[2][4] = {};

  const f16* aB = A + (size_t)m0 * EMB;
  const f16* bB = Bw + (size_t)n0 * EMB;

  // staging map: 1024 chunks per matrix per tile; thread handles chunks tid, tid+512
  int srow[2], scl[2];
#pragma unroll
  for (int p = 0; p < 2; ++p) {
    int c = p * 512 + tid;
    srow[p] = c >> 3;
    scl[p] = (c & 7) ^ (srow[p] & 7);  // pre-swizzled global chunk, linear LDS dest
  }

#define GSTAGE(ktv, bufv)                                                                     \
  {                                                                                           \
    _Pragma("unroll") for (int p = 0; p < 2; ++p) {                                           \
      int c = p * 512 + tid;                                                                  \
      gload_lds16(aB + (size_t)srow[p] * EMB + (ktv) + scl[p] * 8, (char*)sA[bufv] + c * 16); \
      gload_lds16(bB + (size_t)srow[p] * EMB + (ktv) + scl[p] * 8, (char*)sB[bufv] + c * 16); \
    }                                                                                         \
  }

  GSTAGE(0, 0);
  __syncthreads();

  int cur = 0;
  for (int t = 0; t < 8; ++t) {
    if (t < 7) GSTAGE((t + 1) * 64, cur ^ 1);
#pragma unroll
    for (int ks = 0; ks < 2; ++ks) {
      f16x8 af[2], bf[4];
#pragma unroll
      for (int m = 0; m < 2; ++m) {
        int r = wm * 32 + m * 16 + lanelow;
        af[m] = sA[cur][r * 8 + ((ks * 4 + lanehi) ^ (r & 7))];
      }
#pragma unroll
      for (int n = 0; n < 4; ++n) {
        int r = wn * 64 + n * 16 + lanelow;
        bf[n] = sB[cur][r * 8 + ((ks * 4 + lanehi) ^ (r & 7))];
      }
      __builtin_amdgcn_s_setprio(1);
#pragma unroll
      for (int m = 0; m < 2; ++m)
#pragma unroll
        for (int n = 0; n < 4; ++n)
          acc[m][n] = __builtin_amdgcn_mfma_f32_16x16x32_f16(af[m], bf[n], acc[m][n], 0, 0, 0);
      __builtin_amdgcn_s_setprio(0);
    }
    __syncthreads();  // next buffer staged; all waves done with cur
    cur ^= 1;
  }
#undef GSTAGE

  // epilogue: C/D layout col = lane&15, row = (lane>>4)*4 + j
#pragma unroll
  for (int n = 0; n < 4; ++n) {
    int col = n0 + wn * 64 + n * 16 + lanelow;
    float bv = bias[col];
    if (MODE == 1 && (col >> 9) == 2) {
      // V-part: j -> s contiguous in Vt[bh][d][s]; pack 4 per store
      int fr = col & 511, hh = fr >> 6, d = fr & 63;
#pragma unroll
      for (int m = 0; m < 2; ++m) {
        int rbase = m0 + wm * 32 + m * 16 + lanehi * 4;
        int b = rbase >> 10, s = rbase & 1023;
        f16x4 pv = {(f16)(acc[m][n][0] + bv), (f16)(acc[m][n][1] + bv),
                    (f16)(acc[m][n][2] + bv), (f16)(acc[m][n][3] + bv)};
        *(f16x4*)(Vt + ((size_t)(b * NH + hh) * DHEAD + d) * SEQ + s) = pv;
      }
    } else {
#pragma unroll
      for (int m = 0; m < 2; ++m) {
        int rbase = m0 + wm * 32 + m * 16 + lanehi * 4;
#pragma unroll
        for (int j = 0; j < 4; ++j) {
          float v = acc[m][n][j] + bv;
          int row = rbase + j;
          if (MODE == 0) {
            Uout[(size_t)row * EMB + col] = (f16)v;
          } else {
            int part = col >> 9, fr = col & 511;
            int hh = fr >> 6, d = fr & 63;
            int b = row >> 10, s = row & 1023;
            int bh = b * NH + hh;
            if (part == 0)
              Qo[((size_t)bh * SEQ + s) * DHEAD + d] = (f16)v;
            else
              Ko[((size_t)bh * SEQ + s) * DHEAD + d] = (f16)v;
          }
        }
      }
    }
  }
}

// ---------------- flash attention: 8-wave blocks + KVBLK=128 (R13, frozen) ----------------

__global__ __launch_bounds__(512) void k_attn(const f16* __restrict__ Q, const f16* __restrict__ K,
                                              const f16* __restrict__ Vt, const f16* __restrict__ adjP,
                                              f16* __restrict__ Ob) {
  __shared__ __align__(16) f16 sK[2][8192];   // [buf][128 rows x 8 chunks], swizzled (16KB each)
  __shared__ __align__(16) f16 sV[2][8192];   // [buf][64 rows x 16 chunks], swizzled (16KB each)
  __shared__ __align__(16) f16 Pl[8 * 1024];  // per-wave [16][64] P, swizzled (2KB each)
  const int tid = threadIdx.x;
  const int lane = tid & 63;
  const int lanelow = lane & 15, lanehi = lane >> 4;
  const int wave = tid >> 6;  // [0,8)
  f16* Plw = Pl + wave * 1024;

  // XCD-chunked decode (bijective on [0,512)): xcd = flat&7 owns 8 bh, all 8 qblks
  const int flat = blockIdx.x;
  const int bh = (flat & 7) * 8 + ((flat >> 3) & 7);
  const int qblk = flat >> 6;  // [0,8)
  const int b = bh >> 3, hh = bh & 7;
  const int q0 = qblk * 128 + wave * 16;

  const f16* Kbase = K + (size_t)bh * SEQ * DHEAD;
  const f16* Vbase = Vt + (size_t)bh * DHEAD * SEQ;

  // staging maps (linear LDS dest, inverse-swizzled global source).
  int kr[2], kc[2], vr[2], vc[2];
#pragma unroll
  for (int p = 0; p < 2; ++p) {
    int c = p * 512 + tid;
    kr[p] = c >> 3;
    kc[p] = (c & 7) ^ (kr[p] & 7);
    vr[p] = c >> 4;
    vc[p] = (c & 15) ^ (vr[p] & 7);
  }

#define STAGE(tv, bufv)                                                                         \
  {                                                                                             \
    const int kts = (tv)*128;                                                                   \
    _Pragma("unroll") for (int p = 0; p < 2; ++p) {                                             \
      int c = p * 512 + tid;                                                                    \
      gload_lds16(Kbase + (size_t)(kts + kr[p]) * DHEAD + kc[p] * 8, (char*)sK[bufv] + c * 16); \
      gload_lds16(Vbase + (size_t)vr[p] * SEQ + kts + vc[p] * 8, (char*)sV[bufv] + c * 16);     \
    }                                                                                           \
  }

  // hoist Q fragments (16 rows)
  f16x8 qf[2];
#pragma unroll
  for (int ks = 0; ks < 2; ++ks)
    qf[ks] = *(const f16x8*)(Q + ((size_t)bh * SEQ + q0 + lanelow) * DHEAD + ks * 32 + lanehi * 8);

  // adj register prefetch (f16 C-frag packed): 4 x f16x4, indexed by 64-key sub-tile
  const f16* Ab = adjP + ((size_t)(q0 + lanehi * 4) * 256 + lanelow) * 4;
  f16x4 ab[4];
#define LOAD_A(tv)                                                           \
  {                                                                          \
    _Pragma("unroll") for (int j = 0; j < 4; ++j)                            \
        ab[j] = *(const f16x4*)(Ab + ((size_t)j * 256 + (tv)*16) * 4);       \
  }

  f32x4 oacc[4] = {};
  float lpart[4] = {};

  STAGE(0, 0);
  LOAD_A(0);
  __syncthreads();

  int cur = 0;
  for (int t = 0; t < 8; ++t) {
    if (t < 7) STAGE(t + 1, cur ^ 1);

    const f16* sKc = sK[cur];
    const f16* sVc = sV[cur];

#pragma unroll
    for (int hs = 0; hs < 2; ++hs) {
      const int t2 = t * 2 + hs;  // 64-key sub-tile index (0..15)

      // --- QK^T from LDS K (rows hs*64 .. hs*64+63)
      f32x4 sacc[4] = {};
#pragma unroll
      for (int ks = 0; ks < 2; ++ks) {
        f16x8 kf[4];
#pragma unroll
        for (int n = 0; n < 4; ++n) {
          int r = hs * 64 + n * 16 + lanelow;
          kf[n] = *(const f16x8*)(sKc + (r * 8 + ((ks * 4 + lanehi) ^ (r & 7))) * 8);
        }
        __builtin_amdgcn_s_setprio(1);
#pragma unroll
        for (int n = 0; n < 4; ++n)
          sacc[n] = __builtin_amdgcn_mfma_f32_16x16x32_f16(qf[ks], kf[n], sacc[n], 0, 0, 0);
        __builtin_amdgcn_s_setprio(0);
      }

      // snapshot adj(t2), prefetch adj(t2+1)
      f16x4 acur[4];
#pragma unroll
      for (int j = 0; j < 4; ++j) acur[j] = ab[j];
      if (t2 < 15) LOAD_A(t2 + 1);

      // --- exp + PV interleaved by k-half: PV(ks=nh) only needs P cols n=2nh,2nh+1
#pragma unroll
      for (int nh = 0; nh < 2; ++nh) {
#pragma unroll
        for (int j = 0; j < 4; ++j) {
          const int prow = lanehi * 4 + j;
          const f16x4 a4 = acur[j];
#pragma unroll
          for (int nn = 0; nn < 2; ++nn) {
            const int n = nh * 2 + nn;
            float p = EXP2F(sacc[n][j] * (float)a4[n]);
            lpart[j] += p;
            Plw[prow * 64 + (((n * 2 + (lanelow >> 3)) ^ (prow & 7)) * 8) + (lanelow & 7)] = (f16)p;
          }
        }
        f16x8 pa, vf[4];
        pa = *(const f16x8*)(Plw + lanelow * 64 + (((nh * 4 + lanehi) ^ (lanelow & 7)) * 8));
#pragma unroll
        for (int n = 0; n < 4; ++n) {
          int r = n * 16 + lanelow;
          vf[n] = *(const f16x8*)(sVc + (r * 16 + ((hs * 8 + nh * 4 + lanehi) ^ (r & 7))) * 8);
        }
        __builtin_amdgcn_s_setprio(1);
#pragma unroll
        for (int n = 0; n < 4; ++n)
          oacc[n] = __builtin_amdgcn_mfma_f32_16x16x32_f16(pa, vf[n], oacc[n], 0, 0, 0);
        __builtin_amdgcn_s_setprio(0);
      }
    }

    __syncthreads();  // next buffer staged; all waves done with cur
    cur ^= 1;
  }
#undef STAGE
#undef LOAD_A

  // final: cross-lane reduce of row sums, normalize, write O to [B,S,E] f16
  float linv[4];
#pragma unroll
  for (int j = 0; j < 4; ++j) {
    float l = lpart[j];
#pragma unroll
    for (int off = 1; off < 16; off <<= 1) l += __shfl_xor(l, off, 16);
    linv[j] = 1.0f / l;
  }
#pragma unroll
  for (int n = 0; n < 4; ++n)
#pragma unroll
    for (int j = 0; j < 4; ++j) {
      int qrow = q0 + lanehi * 4 + j;
      float v = oacc[n][j] * linv[j];
      Ob[((size_t)b * SEQ + qrow) * EMB + hh * DHEAD + n * 16 + lanelow] = (f16)v;
    }
}

// ---------------- residual + layernorm (wave per row) ----------------
// INH=1 reads f16 xh as residual (layer-1); INH=0 reads f32 x (layer-0).

template <int INH>
__global__ __launch_bounds__(256) void k_ln(const float* __restrict__ xf, const f16* __restrict__ xh_in,
                                            const f16* __restrict__ Uin,
                                            const float* __restrict__ gamma, const float* __restrict__ beta,
                                            float* __restrict__ xout, f16* __restrict__ xh_out) {
  const int row = blockIdx.x * 4 + (threadIdx.x >> 6);
  const int lane = threadIdx.x & 63;
  const size_t base = (size_t)row * EMB + lane * 8;
  float u[8];
  {
    f16x8 uh = *(const f16x8*)(Uin + base);
    if (INH) {
      f16x8 xh8 = *(const f16x8*)(xh_in + base);
#pragma unroll
      for (int i = 0; i < 8; ++i) u[i] = (float)xh8[i] + (float)uh[i];
    } else {
      float4 a0 = *(const float4*)(xf + base);
      float4 a1 = *(const float4*)(xf + base + 4);
      u[0] = a0.x + (float)uh[0]; u[1] = a0.y + (float)uh[1];
      u[2] = a0.z + (float)uh[2]; u[3] = a0.w + (float)uh[3];
      u[4] = a1.x + (float)uh[4]; u[5] = a1.y + (float)uh[5];
      u[6] = a1.z + (float)uh[6]; u[7] = a1.w + (float)uh[7];
    }
  }
  float s = 0.f;
#pragma unroll
  for (int i = 0; i < 8; ++i) s += u[i];
#pragma unroll
  for (int off = 1; off < 64; off <<= 1) s += __shfl_xor(s, off, 64);
  const float mu = s * (1.0f / EMB);
  float v = 0.f;
#pragma unroll
  for (int i = 0; i < 8; ++i) { float d = u[i] - mu; v += d * d; }
#pragma unroll
  for (int off = 1; off < 64; off <<= 1) v += __shfl_xor(v, off, 64);
  const float rs = rsqrtf(v * (1.0f / EMB) + 1e-5f);
  const int ci = lane * 8;
  float4 g0 = *(const float4*)(gamma + ci);
  float4 g1 = *(const float4*)(gamma + ci + 4);
  float4 b0 = *(const float4*)(beta + ci);
  float4 b1 = *(const float4*)(beta + ci + 4);
  float g[8] = {g0.x, g0.y, g0.z, g0.w, g1.x, g1.y, g1.z, g1.w};
  float be[8] = {b0.x, b0.y, b0.z, b0.w, b1.x, b1.y, b1.z, b1.w};
  float o[8];
#pragma unroll
  for (int i = 0; i < 8; ++i) o[i] = (u[i] - mu) * rs * g[i] + be[i];
  if (xout) {
    float4 o0 = {o[0], o[1], o[2], o[3]}, o1 = {o[4], o[5], o[6], o[7]};
    *(float4*)(xout + base) = o0;
    *(float4*)(xout + base + 4) = o1;
  }
  if (xh_out) {
    f16x8 hv = {(f16)o[0], (f16)o[1], (f16)o[2], (f16)o[3], (f16)o[4], (f16)o[5], (f16)o[6], (f16)o[7]};
    *(f16x8*)(xh_out + base) = hv;
  }
}

// ---------------- launch ----------------

extern "C" void kernel_launch(void* const* d_in, const int* in_sizes, int n_in,
                              void* d_out, int out_size, void* d_ws, size_t ws_size,
                              hipStream_t stream) {
  (void)in_sizes; (void)n_in; (void)out_size; (void)ws_size;
  const float* x = (const float*)d_in[0];
  const float* adj = (const float*)d_in[1];
  const float* Wq = (const float*)d_in[2];
  const float* bq = (const float*)d_in[3];
  const float* Wk = (const float*)d_in[4];
  const float* bk = (const float*)d_in[5];
  const float* Wv = (const float*)d_in[6];
  const float* bv = (const float*)d_in[7];
  const float* Wo = (const float*)d_in[8];
  const float* bo = (const float*)d_in[9];
  const float* gamma = (const float*)d_in[10];
  const float* beta = (const float*)d_in[11];

  char* ws = (char*)d_ws;
  size_t off = 0;
  auto alloc = [&](size_t bytes) {
    char* p = ws + off;
    off += (bytes + 255) & ~(size_t)255;
    return p;
  };
  f16* wqkv = (f16*)alloc((size_t)2 * 1536 * 512 * sizeof(f16));
  f16* wo = (f16*)alloc((size_t)2 * 512 * 512 * sizeof(f16));
  float* bqkv = (float*)alloc((size_t)2 * 1536 * sizeof(float));
  f16* adjP = (f16*)alloc((size_t)SEQ * SEQ * sizeof(f16));
  f16* xh = (f16*)alloc((size_t)NTOK * EMB * sizeof(f16));
  f16* Qb = (f16*)alloc((size_t)NTOK * EMB * sizeof(f16));
  f16* Kb = (f16*)alloc((size_t)NTOK * EMB * sizeof(f16));
  f16* Vtb = (f16*)alloc((size_t)NTOK * EMB * sizeof(f16));
  f16* Ob = (f16*)alloc((size_t)NTOK * EMB * sizeof(f16));
  f16* U = (f16*)alloc((size_t)NTOK * EMB * sizeof(f16));

  k_pack_w<<<1536, 256, 0, stream>>>(Wq, Wk, Wv, Wo, wqkv, wo);
  k_pack_b<<<12, 256, 0, stream>>>(bq, bk, bv, bqkv);
  k_pack_adjP<<<1024, 256, 0, stream>>>(adj, adjP);
  k_cvt<<<2048, 256, 0, stream>>>(x, xh);

  for (int l = 0; l < 2; ++l) {
    k_gemm<1><<<768, 512, 0, stream>>>(xh, wqkv + (size_t)l * 1536 * 512, bqkv + l * 1536,
                                       nullptr, Qb, Kb, Vtb);
    k_attn<<<512, 512, 0, stream>>>(Qb, Kb, Vtb, adjP, Ob);
    k_gemm<0><<<256, 512, 0, stream>>>(Ob, wo + (size_t)l * 512 * 512, bo + l * 512,
                                       U, nullptr, nullptr, nullptr);
    if (l == 0)
      k_ln<0><<<2048, 256, 0, stream>>>(x, nullptr, U, gamma, beta, nullptr, xh);
    else
      k_ln<1><<<2048, 256, 0, stream>>>(nullptr, xh, U, gamma + 512, beta + 512, (float*)d_out, nullptr);
  }
}

// Round 16
// 156.936 us; speedup vs baseline: 1.0444x; 1.0444x over previous
//
#include <hip/hip_runtime.h>
#include <stdint.h>

typedef _Float16 f16;
typedef _Float16 f16x8 __attribute__((ext_vector_type(8)));
typedef _Float16 f16x4 __attribute__((ext_vector_type(4)));
typedef float f32x4 __attribute__((ext_vector_type(4)));

constexpr int EMB = 512;
constexpr int SEQ = 1024;
constexpr int NH = 8;
constexpr int DHEAD = 64;
constexpr int NTOK = 8192;  // B*S

#define GAS __attribute__((address_space(1)))
#define LAS __attribute__((address_space(3)))

#if __has_builtin(__builtin_amdgcn_exp2f)
#define EXP2F(x) __builtin_amdgcn_exp2f(x)
#else
#define EXP2F(x) exp2f(x)
#endif

static __device__ __forceinline__ void gload_lds16(const void* g, void* l) {
  __builtin_amdgcn_global_load_lds((const GAS void*)g, (LAS void*)l, 16, 0, 0);
}

// ---------------- fused preamble: cvt | pack_w | pack_adjP | pack_b ----------------
// R15: one dispatch instead of four (saves 3 inter-dispatch drains; the four
// independent tasks co-schedule across the GPU). Branch is block-uniform.
// Block ranges: [0,2048) cvt x->xh; [2048,3584) pack_w; [3584,4608) pack_adjP;
// [4608,4620) pack_b.

__global__ __launch_bounds__(256) void k_prep(const float* __restrict__ x, const float* __restrict__ adj,
                                              const float* __restrict__ Wq, const float* __restrict__ Wk,
                                              const float* __restrict__ Wv, const float* __restrict__ Wo,
                                              const float* __restrict__ bq, const float* __restrict__ bk,
                                              const float* __restrict__ bv,
                                              f16* __restrict__ xh, f16* __restrict__ wqkv,
                                              f16* __restrict__ wo, f16* __restrict__ adjP,
                                              float* __restrict__ bqkv) {
  const int bid = blockIdx.x;
  if (bid < 2048) {
    // x (f32) -> xh (f16), 8 elems/thread
    int i = (bid * 256 + threadIdx.x) * 8;
    float4 a = *(const float4*)(x + i);
    float4 b = *(const float4*)(x + i + 4);
    f16x8 h = {(f16)a.x, (f16)a.y, (f16)a.z, (f16)a.w, (f16)b.x, (f16)b.y, (f16)b.z, (f16)b.w};
    *(f16x8*)(xh + i) = h;
  } else if (bid < 3584) {
    int tid = (bid - 2048) * 256 + threadIdx.x;
    if (tid < 2 * 1536 * 128) {  // qkv: [L][1536][512], 4 elems/thread
      int e4 = tid & 127;
      int f = (tid >> 7) % 1536;
      int l = tid / (128 * 1536);
      int part = f >> 9, fr = f & 511;
      const float* src = (part == 0 ? Wq : part == 1 ? Wk : Wv) + (size_t)l * EMB * EMB + (size_t)fr * EMB + e4 * 4;
      float4 v = *(const float4*)src;
      f16x4 hv = {(f16)v.x, (f16)v.y, (f16)v.z, (f16)v.w};
      *(f16x4*)(wqkv + ((size_t)l * 1536 + f) * EMB + e4 * 4) = hv;
    }
    if (tid < 2 * 512 * 128) {  // wo: [L][512][512]
      int e4 = tid & 127;
      int f = (tid >> 7) % 512;
      int l = tid / (128 * 512);
      float4 v = *(const float4*)(Wo + (size_t)l * EMB * EMB + (size_t)f * EMB + e4 * 4);
      f16x4 hv = {(f16)v.x, (f16)v.y, (f16)v.z, (f16)v.w};
      *(f16x4*)(wo + ((size_t)l * 512 + f) * EMB + e4 * 4) = hv;
    }
  } else if (bid < 4608) {
    // adj -> f16 pre-scaled by 0.125*log2(e), packed in MFMA C-fragment order
    int tid = (bid - 3584) * 256 + threadIdx.x;  // 262144 total
    int lo = tid & 15, t = (tid >> 4) & 15, qrow = tid >> 8;
    const float c = 0.125f * 1.44269504088896f;
    const float* row = adj + (size_t)qrow * SEQ + t * 64 + lo;
    f16x4 v = {(f16)(row[0] * c), (f16)(row[16] * c), (f16)(row[32] * c), (f16)(row[48] * c)};
    *(f16x4*)(adjP + (size_t)tid * 4) = v;
  } else {
    int tid = (bid - 4608) * 256 + threadIdx.x;
    if (tid < 2 * 1536) {
      int f = tid % 1536, l = tid / 1536;
      int part = f >> 9, fr = f & 511;
      bqkv[tid] = (part == 0 ? bq : part == 1 ? bk : bv)[l * EMB + fr];
    }
  }
}

// ---------------- GEMM: C[M,N] = A[M,512] * Bw[N,512]^T + bias ----------------
// R14 8-wave structure (frozen; gemm has held ~22us across 4 shapes).
// 512 threads, waves 4x2, wave owns 32x64 (acc 2x4). BK=64, 8 K-steps,
// 2-buffer LDS (64KB), STAGE(t+1) at top, one __syncthreads at end.

template <int MODE>
__global__ __launch_bounds__(512) void k_gemm(const f16* __restrict__ A, const f16* __restrict__ Bw,
                                              const float* __restrict__ bias, f16* __restrict__ Uout,
                                              f16* __restrict__ Qo, f16* __restrict__ Ko,
                                              f16* __restrict__ Vt) {
  __shared__ f16x8 sA[2][1024];  // [buf][128 rows x 8 chunks] = 16KB each
  __shared__ f16x8 sB[2][1024];
  const int tid = threadIdx.x;
  const int lane = tid & 63;
  const int lanelow = lane & 15, lanehi = lane >> 4;
  const int wave = tid >> 6;          // [0,8)
  const int wm = wave >> 1;           // [0,4) -> 32-row slab
  const int wn = wave & 1;            // [0,2) -> 64-col slab
  const int flat = blockIdx.x;
  const int mt = (flat & 7) * 8 + ((flat >> 3) & 7);
  const int nt = flat >> 6;
  const int m0 = mt * 128, n0 = nt * 128;

  f32x4 acc[2][4] = {};

  const f16* aB = A + (size_t)m0 * EMB;
  const f16* bB = Bw + (size_t)n0 * EMB;

  // staging map: 1024 chunks per matrix per tile; thread handles chunks tid, tid+512
  int srow[2], scl[2];
#pragma unroll
  for (int p = 0; p < 2; ++p) {
    int c = p * 512 + tid;
    srow[p] = c >> 3;
    scl[p] = (c & 7) ^ (srow[p] & 7);  // pre-swizzled global chunk, linear LDS dest
  }

#define GSTAGE(ktv, bufv)                                                                     \
  {                                                                                           \
    _Pragma("unroll") for (int p = 0; p < 2; ++p) {                                           \
      int c = p * 512 + tid;                                                                  \
      gload_lds16(aB + (size_t)srow[p] * EMB + (ktv) + scl[p] * 8, (char*)sA[bufv] + c * 16); \
      gload_lds16(bB + (size_t)srow[p] * EMB + (ktv) + scl[p] * 8, (char*)sB[bufv] + c * 16); \
    }                                                                                         \
  }

  GSTAGE(0, 0);
  __syncthreads();

  int cur = 0;
  for (int t = 0; t < 8; ++t) {
    if (t < 7) GSTAGE((t + 1) * 64, cur ^ 1);
#pragma unroll
    for (int ks = 0; ks < 2; ++ks) {
      f16x8 af[2], bf[4];
#pragma unroll
      for (int m = 0; m < 2; ++m) {
        int r = wm * 32 + m * 16 + lanelow;
        af[m] = sA[cur][r * 8 + ((ks * 4 + lanehi) ^ (r & 7))];
      }
#pragma unroll
      for (int n = 0; n < 4; ++n) {
        int r = wn * 64 + n * 16 + lanelow;
        bf[n] = sB[cur][r * 8 + ((ks * 4 + lanehi) ^ (r & 7))];
      }
      __builtin_amdgcn_s_setprio(1);
#pragma unroll
      for (int m = 0; m < 2; ++m)
#pragma unroll
        for (int n = 0; n < 4; ++n)
          acc[m][n] = __builtin_amdgcn_mfma_f32_16x16x32_f16(af[m], bf[n], acc[m][n], 0, 0, 0);
      __builtin_amdgcn_s_setprio(0);
    }
    __syncthreads();  // next buffer staged; all waves done with cur
    cur ^= 1;
  }
#undef GSTAGE

  // epilogue: C/D layout col = lane&15, row = (lane>>4)*4 + j
#pragma unroll
  for (int n = 0; n < 4; ++n) {
    int col = n0 + wn * 64 + n * 16 + lanelow;
    float bv = bias[col];
    if (MODE == 1 && (col >> 9) == 2) {
      // V-part: j -> s contiguous in Vt[bh][d][s]; pack 4 per store
      int fr = col & 511, hh = fr >> 6, d = fr & 63;
#pragma unroll
      for (int m = 0; m < 2; ++m) {
        int rbase = m0 + wm * 32 + m * 16 + lanehi * 4;
        int b = rbase >> 10, s = rbase & 1023;
        f16x4 pv = {(f16)(acc[m][n][0] + bv), (f16)(acc[m][n][1] + bv),
                    (f16)(acc[m][n][2] + bv), (f16)(acc[m][n][3] + bv)};
        *(f16x4*)(Vt + ((size_t)(b * NH + hh) * DHEAD + d) * SEQ + s) = pv;
      }
    } else {
#pragma unroll
      for (int m = 0; m < 2; ++m) {
        int rbase = m0 + wm * 32 + m * 16 + lanehi * 4;
#pragma unroll
        for (int j = 0; j < 4; ++j) {
          float v = acc[m][n][j] + bv;
          int row = rbase + j;
          if (MODE == 0) {
            Uout[(size_t)row * EMB + col] = (f16)v;
          } else {
            int part = col >> 9, fr = col & 511;
            int hh = fr >> 6, d = fr & 63;
            int b = row >> 10, s = row & 1023;
            int bh = b * NH + hh;
            if (part == 0)
              Qo[((size_t)bh * SEQ + s) * DHEAD + d] = (f16)v;
            else
              Ko[((size_t)bh * SEQ + s) * DHEAD + d] = (f16)v;
          }
        }
      }
    }
  }
}

// ---------------- flash attention: 8-wave blocks + KVBLK=128 (R13, frozen) ----------------

__global__ __launch_bounds__(512) void k_attn(const f16* __restrict__ Q, const f16* __restrict__ K,
                                              const f16* __restrict__ Vt, const f16* __restrict__ adjP,
                                              f16* __restrict__ Ob) {
  __shared__ __align__(16) f16 sK[2][8192];   // [buf][128 rows x 8 chunks], swizzled (16KB each)
  __shared__ __align__(16) f16 sV[2][8192];   // [buf][64 rows x 16 chunks], swizzled (16KB each)
  __shared__ __align__(16) f16 Pl[8 * 1024];  // per-wave [16][64] P, swizzled (2KB each)
  const int tid = threadIdx.x;
  const int lane = tid & 63;
  const int lanelow = lane & 15, lanehi = lane >> 4;
  const int wave = tid >> 6;  // [0,8)
  f16* Plw = Pl + wave * 1024;

  // XCD-chunked decode (bijective on [0,512)): xcd = flat&7 owns 8 bh, all 8 qblks
  const int flat = blockIdx.x;
  const int bh = (flat & 7) * 8 + ((flat >> 3) & 7);
  const int qblk = flat >> 6;  // [0,8)
  const int b = bh >> 3, hh = bh & 7;
  const int q0 = qblk * 128 + wave * 16;

  const f16* Kbase = K + (size_t)bh * SEQ * DHEAD;
  const f16* Vbase = Vt + (size_t)bh * DHEAD * SEQ;

  // staging maps (linear LDS dest, inverse-swizzled global source).
  int kr[2], kc[2], vr[2], vc[2];
#pragma unroll
  for (int p = 0; p < 2; ++p) {
    int c = p * 512 + tid;
    kr[p] = c >> 3;
    kc[p] = (c & 7) ^ (kr[p] & 7);
    vr[p] = c >> 4;
    vc[p] = (c & 15) ^ (vr[p] & 7);
  }

#define STAGE(tv, bufv)                                                                         \
  {                                                                                             \
    const int kts = (tv)*128;                                                                   \
    _Pragma("unroll") for (int p = 0; p < 2; ++p) {                                             \
      int c = p * 512 + tid;                                                                    \
      gload_lds16(Kbase + (size_t)(kts + kr[p]) * DHEAD + kc[p] * 8, (char*)sK[bufv] + c * 16); \
      gload_lds16(Vbase + (size_t)vr[p] * SEQ + kts + vc[p] * 8, (char*)sV[bufv] + c * 16);     \
    }                                                                                           \
  }

  // hoist Q fragments (16 rows)
  f16x8 qf[2];
#pragma unroll
  for (int ks = 0; ks < 2; ++ks)
    qf[ks] = *(const f16x8*)(Q + ((size_t)bh * SEQ + q0 + lanelow) * DHEAD + ks * 32 + lanehi * 8);

  // adj register prefetch (f16 C-frag packed): 4 x f16x4, indexed by 64-key sub-tile
  const f16* Ab = adjP + ((size_t)(q0 + lanehi * 4) * 256 + lanelow) * 4;
  f16x4 ab[4];
#define LOAD_A(tv)                                                           \
  {                                                                          \
    _Pragma("unroll") for (int j = 0; j < 4; ++j)                            \
        ab[j] = *(const f16x4*)(Ab + ((size_t)j * 256 + (tv)*16) * 4);       \
  }

  f32x4 oacc[4] = {};
  float lpart[4] = {};

  STAGE(0, 0);
  LOAD_A(0);
  __syncthreads();

  int cur = 0;
  for (int t = 0; t < 8; ++t) {
    if (t < 7) STAGE(t + 1, cur ^ 1);

    const f16* sKc = sK[cur];
    const f16* sVc = sV[cur];

#pragma unroll
    for (int hs = 0; hs < 2; ++hs) {
      const int t2 = t * 2 + hs;  // 64-key sub-tile index (0..15)

      // --- QK^T from LDS K (rows hs*64 .. hs*64+63)
      f32x4 sacc[4] = {};
#pragma unroll
      for (int ks = 0; ks < 2; ++ks) {
        f16x8 kf[4];
#pragma unroll
        for (int n = 0; n < 4; ++n) {
          int r = hs * 64 + n * 16 + lanelow;
          kf[n] = *(const f16x8*)(sKc + (r * 8 + ((ks * 4 + lanehi) ^ (r & 7))) * 8);
        }
        __builtin_amdgcn_s_setprio(1);
#pragma unroll
        for (int n = 0; n < 4; ++n)
          sacc[n] = __builtin_amdgcn_mfma_f32_16x16x32_f16(qf[ks], kf[n], sacc[n], 0, 0, 0);
        __builtin_amdgcn_s_setprio(0);
      }

      // snapshot adj(t2), prefetch adj(t2+1)
      f16x4 acur[4];
#pragma unroll
      for (int j = 0; j < 4; ++j) acur[j] = ab[j];
      if (t2 < 15) LOAD_A(t2 + 1);

      // --- exp + PV interleaved by k-half: PV(ks=nh) only needs P cols n=2nh,2nh+1
#pragma unroll
      for (int nh = 0; nh < 2; ++nh) {
#pragma unroll
        for (int j = 0; j < 4; ++j) {
          const int prow = lanehi * 4 + j;
          const f16x4 a4 = acur[j];
#pragma unroll
          for (int nn = 0; nn < 2; ++nn) {
            const int n = nh * 2 + nn;
            float p = EXP2F(sacc[n][j] * (float)a4[n]);
            lpart[j] += p;
            Plw[prow * 64 + (((n * 2 + (lanelow >> 3)) ^ (prow & 7)) * 8) + (lanelow & 7)] = (f16)p;
          }
        }
        f16x8 pa, vf[4];
        pa = *(const f16x8*)(Plw + lanelow * 64 + (((nh * 4 + lanehi) ^ (lanelow & 7)) * 8));
#pragma unroll
        for (int n = 0; n < 4; ++n) {
          int r = n * 16 + lanelow;
          vf[n] = *(const f16x8*)(sVc + (r * 16 + ((hs * 8 + nh * 4 + lanehi) ^ (r & 7))) * 8);
        }
        __builtin_amdgcn_s_setprio(1);
#pragma unroll
        for (int n = 0; n < 4; ++n)
          oacc[n] = __builtin_amdgcn_mfma_f32_16x16x32_f16(pa, vf[n], oacc[n], 0, 0, 0);
        __builtin_amdgcn_s_setprio(0);
      }
    }

    __syncthreads();  // next buffer staged; all waves done with cur
    cur ^= 1;
  }
#undef STAGE
#undef LOAD_A

  // final: cross-lane reduce of row sums, normalize, write O to [B,S,E] f16
  float linv[4];
#pragma unroll
  for (int j = 0; j < 4; ++j) {
    float l = lpart[j];
#pragma unroll
    for (int off = 1; off < 16; off <<= 1) l += __shfl_xor(l, off, 16);
    linv[j] = 1.0f / l;
  }
#pragma unroll
  for (int n = 0; n < 4; ++n)
#pragma unroll
    for (int j = 0; j < 4; ++j) {
      int qrow = q0 + lanehi * 4 + j;
      float v = oacc[n][j] * linv[j];
      Ob[((size_t)b * SEQ + qrow) * EMB + hh * DHEAD + n * 16 + lanelow] = (f16)v;
    }
}

// ---------------- residual + layernorm (wave per row) ----------------
// INH=1 reads f16 xh as residual (layer-1); INH=0 reads f32 x (layer-0).

template <int INH>
__global__ __launch_bounds__(256) void k_ln(const float* __restrict__ xf, const f16* __restrict__ xh_in,
                                            const f16* __restrict__ Uin,
                                            const float* __restrict__ gamma, const float* __restrict__ beta,
                                            float* __restrict__ xout, f16* __restrict__ xh_out) {
  const int row = blockIdx.x * 4 + (threadIdx.x >> 6);
  const int lane = threadIdx.x & 63;
  const size_t base = (size_t)row * EMB + lane * 8;
  float u[8];
  {
    f16x8 uh = *(const f16x8*)(Uin + base);
    if (INH) {
      f16x8 xh8 = *(const f16x8*)(xh_in + base);
#pragma unroll
      for (int i = 0; i < 8; ++i) u[i] = (float)xh8[i] + (float)uh[i];
    } else {
      float4 a0 = *(const float4*)(xf + base);
      float4 a1 = *(const float4*)(xf + base + 4);
      u[0] = a0.x + (float)uh[0]; u[1] = a0.y + (float)uh[1];
      u[2] = a0.z + (float)uh[2]; u[3] = a0.w + (float)uh[3];
      u[4] = a1.x + (float)uh[4]; u[5] = a1.y + (float)uh[5];
      u[6] = a1.z + (float)uh[6]; u[7] = a1.w + (float)uh[7];
    }
  }
  float s = 0.f;
#pragma unroll
  for (int i = 0; i < 8; ++i) s += u[i];
#pragma unroll
  for (int off = 1; off < 64; off <<= 1) s += __shfl_xor(s, off, 64);
  const float mu = s * (1.0f / EMB);
  float v = 0.f;
#pragma unroll
  for (int i = 0; i < 8; ++i) { float d = u[i] - mu; v += d * d; }
#pragma unroll
  for (int off = 1; off < 64; off <<= 1) v += __shfl_xor(v, off, 64);
  const float rs = rsqrtf(v * (1.0f / EMB) + 1e-5f);
  const int ci = lane * 8;
  float4 g0 = *(const float4*)(gamma + ci);
  float4 g1 = *(const float4*)(gamma + ci + 4);
  float4 b0 = *(const float4*)(beta + ci);
  float4 b1 = *(const float4*)(beta + ci + 4);
  float g[8] = {g0.x, g0.y, g0.z, g0.w, g1.x, g1.y, g1.z, g1.w};
  float be[8] = {b0.x, b0.y, b0.z, b0.w, b1.x, b1.y, b1.z, b1.w};
  float o[8];
#pragma unroll
  for (int i = 0; i < 8; ++i) o[i] = (u[i] - mu) * rs * g[i] + be[i];
  if (xout) {
    float4 o0 = {o[0], o[1], o[2], o[3]}, o1 = {o[4], o[5], o[6], o[7]};
    *(float4*)(xout + base) = o0;
    *(float4*)(xout + base + 4) = o1;
  }
  if (xh_out) {
    f16x8 hv = {(f16)o[0], (f16)o[1], (f16)o[2], (f16)o[3], (f16)o[4], (f16)o[5], (f16)o[6], (f16)o[7]};
    *(f16x8*)(xh_out + base) = hv;
  }
}

// ---------------- launch ----------------

extern "C" void kernel_launch(void* const* d_in, const int* in_sizes, int n_in,
                              void* d_out, int out_size, void* d_ws, size_t ws_size,
                              hipStream_t stream) {
  (void)in_sizes; (void)n_in; (void)out_size; (void)ws_size;
  const float* x = (const float*)d_in[0];
  const float* adj = (const float*)d_in[1];
  const float* Wq = (const float*)d_in[2];
  const float* bq = (const float*)d_in[3];
  const float* Wk = (const float*)d_in[4];
  const float* bk = (const float*)d_in[5];
  const float* Wv = (const float*)d_in[6];
  const float* bv = (const float*)d_in[7];
  const float* Wo = (const float*)d_in[8];
  const float* bo = (const float*)d_in[9];
  const float* gamma = (const float*)d_in[10];
  const float* beta = (const float*)d_in[11];

  char* ws = (char*)d_ws;
  size_t off = 0;
  auto alloc = [&](size_t bytes) {
    char* p = ws + off;
    off += (bytes + 255) & ~(size_t)255;
    return p;
  };
  f16* wqkv = (f16*)alloc((size_t)2 * 1536 * 512 * sizeof(f16));
  f16* wo = (f16*)alloc((size_t)2 * 512 * 512 * sizeof(f16));
  float* bqkv = (float*)alloc((size_t)2 * 1536 * sizeof(float));
  f16* adjP = (f16*)alloc((size_t)SEQ * SEQ * sizeof(f16));
  f16* xh = (f16*)alloc((size_t)NTOK * EMB * sizeof(f16));
  f16* Qb = (f16*)alloc((size_t)NTOK * EMB * sizeof(f16));
  f16* Kb = (f16*)alloc((size_t)NTOK * EMB * sizeof(f16));
  f16* Vtb = (f16*)alloc((size_t)NTOK * EMB * sizeof(f16));
  f16* Ob = (f16*)alloc((size_t)NTOK * EMB * sizeof(f16));
  f16* U = (f16*)alloc((size_t)NTOK * EMB * sizeof(f16));

  k_prep<<<4620, 256, 0, stream>>>(x, adj, Wq, Wk, Wv, Wo, bq, bk, bv,
                                   xh, wqkv, wo, adjP, bqkv);

  for (int l = 0; l < 2; ++l) {
    k_gemm<1><<<768, 512, 0, stream>>>(xh, wqkv + (size_t)l * 1536 * 512, bqkv + l * 1536,
                                       nullptr, Qb, Kb, Vtb);
    k_attn<<<512, 512, 0, stream>>>(Qb, Kb, Vtb, adjP, Ob);
    k_gemm<0><<<256, 512, 0, stream>>>(Ob, wo + (size_t)l * 512 * 512, bo + l * 512,
                                       U, nullptr, nullptr, nullptr);
    if (l == 0)
      k_ln<0><<<2048, 256, 0, stream>>>(x, nullptr, U, gamma, beta, nullptr, xh);
    else
      k_ln<1><<<2048, 256, 0, stream>>>(nullptr, xh, U, gamma + 512, beta + 512, (float*)d_out, nullptr);
  }
}